// Round 16
// baseline (285.388 us; speedup 1.0000x reference)
//
#include <hip/hip_runtime.h>
#include <math.h>

typedef __bf16 bf16_t;
typedef __bf16 bf16x8 __attribute__((ext_vector_type(8)));
typedef float f32x4 __attribute__((ext_vector_type(4)));

#define B_    2
#define LQ    4096
#define LK    1024
#define QDIM  2048
#define KVDIM 2048
#define H_    16
#define HD_   128
#define KVC_  512
#define QC_   768
#define R_    64

// fused row widths
#define QCOMB 3072   // [q_nope(2048) | q_rope(1024)]
#define KCOMB 4352   // [k_nope(2048) | v(2048) | k_rope(64) | pad(192)] -- 17x256 tiles

#define NL_ROPE (-9.210340371976184f / 32.0f)   // -ln(10000)/half
#define NATT   ((B_ * LQ) / 4)                  // 2048 attn blocks
#define WO_TILES 4096                           // (2048/32)*(2048/32)

typedef __attribute__((address_space(1))) void gvoid_t;
typedef __attribute__((address_space(3))) void lvoid_t;

static __device__ __forceinline__ void gld_lds16(const void* g, void* l) {
  __builtin_amdgcn_global_load_lds((gvoid_t*)(void*)g, (lvoid_t*)l, 16, 0, 0);
}

// inline hw transcendentals (no libm calls -> no spills around epilogue trig)
static __device__ __forceinline__ float fexp(float x) {
  return __builtin_amdgcn_exp2f(x * 1.4426950408889634f);   // v_exp_f32
}
static __device__ __forceinline__ void fsincos(float ang, float* s, float* c) {
  float rev = ang * 0.15915494309189535f;                   // radians -> revolutions
  rev -= floorf(rev);                                       // reduce to [0,1) (hw range)
  *s = __builtin_amdgcn_sinf(rev);                          // v_sin_f32: sin(2*pi*rev)
  *c = __builtin_amdgcn_cosf(rev);                          // v_cos_f32
}

// ---------------- weight-transpose descriptor ----------------
struct TransAll {
  const float* src[8];
  bf16_t* dst[8];
  int K[8], N[8], gx[8];
  int off[9];
};

// one 32x32 transpose tile: in (K x N) fp32 -> out (N x K) bf16
static __device__ __forceinline__ void trans_tile(
    const float* __restrict__ src, bf16_t* __restrict__ dst, int K, int N,
    int bx, int by, int x, int y, float* tb /* 32*33 floats */) {
#pragma unroll
  for (int j = 0; j < 32; j += 8)
    tb[(y + j) * 33 + x] = src[(size_t)(by + y + j) * N + bx + x];
  __syncthreads();
#pragma unroll
  for (int j = 0; j < 32; j += 8)
    dst[(size_t)(bx + y + j) * K + by + x] = (bf16_t)tb[x * 33 + (y + j)];
}

// ---------------- prep1: fp32->bf16 convert (q,kv) + W_kvc/W_dq transposes ----------------
#define NCVT 4096
__global__ __launch_bounds__(256) void prep_all(
    const float* __restrict__ qa, bf16_t* __restrict__ oq, long nq,
    const float* __restrict__ kva, bf16_t* __restrict__ okv, long nkv,
    TransAll d) {
  __shared__ float t[32 * 33];
  const int bid = blockIdx.x;
  if (bid < NCVT) {
    const long stride = (long)NCVT * 256 * 8;
    for (long i = ((long)bid * 256 + threadIdx.x) * 8; i < nq; i += stride) {
      float4 x = *(const float4*)(qa + i);
      float4 y = *(const float4*)(qa + i + 4);
      bf16x8 v;
      v[0] = (bf16_t)x.x; v[1] = (bf16_t)x.y; v[2] = (bf16_t)x.z; v[3] = (bf16_t)x.w;
      v[4] = (bf16_t)y.x; v[5] = (bf16_t)y.y; v[6] = (bf16_t)y.z; v[7] = (bf16_t)y.w;
      *(bf16x8*)(oq + i) = v;
    }
    for (long i = ((long)bid * 256 + threadIdx.x) * 8; i < nkv; i += stride) {
      float4 x = *(const float4*)(kva + i);
      float4 y = *(const float4*)(kva + i + 4);
      bf16x8 v;
      v[0] = (bf16_t)x.x; v[1] = (bf16_t)x.y; v[2] = (bf16_t)x.z; v[3] = (bf16_t)x.w;
      v[4] = (bf16_t)y.x; v[5] = (bf16_t)y.y; v[6] = (bf16_t)y.z; v[7] = (bf16_t)y.w;
      *(bf16x8*)(okv + i) = v;
    }
    return;
  }
  const int tb = bid - NCVT;
  int i = 0;
#pragma unroll
  for (int j = 1; j < 8; ++j) if (tb >= d.off[j]) i = j;
  const int local = tb - d.off[i];
  const int gx = d.gx[i];
  trans_tile(d.src[i], d.dst[i], d.K[i], d.N[i],
             (local % gx) * 32, (local / gx) * 32,
             threadIdx.x & 31, threadIdx.x >> 5, t);
}

// ---------------- big2 pipeline body: BM=256, BN=TN, BK=64, 8 waves (2Mx4N) ----------------
template <int TN, typename CT>
__device__ __forceinline__ void big2_body(
    const bf16_t* __restrict__ A, const bf16_t* __restrict__ Bt, CT* __restrict__ C,
    int N, int K, int row0, int col0, bf16_t* lA, bf16_t* lB) {
  constexpr int NF = TN / 64;
  constexpr int LW = 4 + TN / 64;
  const int tid = threadIdx.x;
  const int w = tid >> 6, lane = tid & 63;
  const int wm = w >> 2, wn = w & 3;
  const int lr = lane >> 3;
  const int kswz = ((lane & 7) ^ lr) * 8;
  const int nt = K >> 6;
  const int fr = lane & 15, fq = lane >> 4;

  auto STAGE = [&](int t, int buf) {
    const int k0 = t << 6;
#pragma unroll
    for (int j = 0; j < 4; ++j) {
      const int s = j * 8 + w;
      gld_lds16(A + (size_t)(row0 + s * 8 + lr) * K + k0 + kswz, &lA[buf * 256 * 64 + s * 512]);
    }
#pragma unroll
    for (int j = 0; j < TN / 64; ++j) {
      const int s = j * 8 + w;
      gld_lds16(Bt + (size_t)(col0 + s * 8 + lr) * K + k0 + kswz, &lB[buf * TN * 64 + s * 512]);
    }
  };

  bf16x8 aA[8], bA[NF], aB[8], bB[NF];
  f32x4 acc[8][NF];
#pragma unroll
  for (int i = 0; i < 8; ++i)
#pragma unroll
    for (int j = 0; j < NF; ++j) acc[i][j] = f32x4{0.f, 0.f, 0.f, 0.f};

  auto READ = [&](int buf, int kk, bf16x8* a, bf16x8* b) {
    const int swzk = (kk * 32 + fq * 8) ^ ((fr & 7) << 3);
#pragma unroll
    for (int mf = 0; mf < 8; ++mf)
      a[mf] = *(const bf16x8*)&lA[buf * 256 * 64 + (wm * 128 + mf * 16 + fr) * 64 + swzk];
#pragma unroll
    for (int nf = 0; nf < NF; ++nf)
      b[nf] = *(const bf16x8*)&lB[buf * TN * 64 + (wn * (TN / 4) + nf * 16 + fr) * 64 + swzk];
  };
  auto MF = [&](bf16x8* a, bf16x8* b) {
    __builtin_amdgcn_s_setprio(1);
#pragma unroll
    for (int mf = 0; mf < 8; ++mf)
#pragma unroll
      for (int nf = 0; nf < NF; ++nf)
        acc[mf][nf] = __builtin_amdgcn_mfma_f32_16x16x32_bf16(a[mf], b[nf], acc[mf][nf], 0, 0, 0);
    __builtin_amdgcn_s_setprio(0);
  };

  STAGE(0, 0);
  STAGE(1, 1);
  if constexpr (LW == 8) { asm volatile("s_waitcnt vmcnt(8)" ::: "memory"); }
  else                   { asm volatile("s_waitcnt vmcnt(6)" ::: "memory"); }
  __builtin_amdgcn_sched_barrier(0);
  __builtin_amdgcn_s_barrier();
  READ(0, 0, aA, bA);

  for (int t = 0; t < nt; ++t) {
    const int buf = t & 1;
    READ(buf, 1, aB, bB);
    __builtin_amdgcn_sched_barrier(0);
    MF(aA, bA);
    asm volatile("s_waitcnt lgkmcnt(0)" ::: "memory");
    __builtin_amdgcn_sched_barrier(0);
    __builtin_amdgcn_s_barrier();
    if (t + 2 < nt) {
      STAGE(t + 2, buf);
      if constexpr (LW == 8) { asm volatile("s_waitcnt vmcnt(8)" ::: "memory"); }
      else                   { asm volatile("s_waitcnt vmcnt(6)" ::: "memory"); }
    } else {
      asm volatile("s_waitcnt vmcnt(0)" ::: "memory");
    }
    __builtin_amdgcn_sched_barrier(0);
    __builtin_amdgcn_s_barrier();
    if (t + 1 < nt) READ(buf ^ 1, 0, aA, bA);
    __builtin_amdgcn_sched_barrier(0);
    MF(aB, bB);
  }

#pragma unroll
  for (int mf = 0; mf < 8; ++mf)
#pragma unroll
    for (int nf = 0; nf < NF; ++nf) {
      const int col = col0 + wn * (TN / 4) + nf * 16 + fr;
#pragma unroll
      for (int r = 0; r < 4; ++r) {
        const int row = row0 + wm * 128 + mf * 16 + fq * 4 + r;
        C[(size_t)row * N + col] = (CT)acc[mf][nf][r];
      }
    }
}

// ---------------- dual big2 + packed weight transposes, one launch ----------------
// Blocks [0,192): q_dq (swizzled within 192). [192,224): kv_c (swizzled within 32).
// [224, 224 + ntiles/2): weight transposes for up_fused's weights (2 tiles/block,
// two parallel 256-thread groups; LDS reuses lA). ntiles even. Block-uniform branches.
__global__ __launch_bounds__(512, 2) void gemm_dual_prep(
    const bf16_t* __restrict__ A0, const bf16_t* __restrict__ B0, bf16_t* __restrict__ C0,
    int N0, int K0,
    const bf16_t* __restrict__ A1, const bf16_t* __restrict__ B1, bf16_t* __restrict__ C1,
    int N1, int K1, TransAll d) {
  __shared__ __align__(16) bf16_t lA[2 * 256 * 64];
  __shared__ __align__(16) bf16_t lB[2 * 128 * 64];
  const int orig = blockIdx.x;
  if (orig < 192) {
    const int wg = (orig & 7) * 24 + (orig >> 3);
    const int gx = N0 / 128;
    big2_body<128, bf16_t>(A0, B0, C0, N0, K0, (wg / gx) * 256, (wg % gx) * 128, lA, lB);
  } else if (orig < 224) {
    const int l = orig - 192;
    const int wg = (l & 7) * 4 + (l >> 3);
    const int gx = N1 / 128;
    big2_body<128, bf16_t>(A1, B1, C1, N1, K1, (wg / gx) * 256, (wg % gx) * 128, lA, lB);
  } else {
    const int grp = threadIdx.x >> 8;           // 0/1
    const int tt = threadIdx.x & 255;
    const int tile = (orig - 224) * 2 + grp;
    int i = 0;
#pragma unroll
    for (int j = 1; j < 8; ++j) if (tile >= d.off[j]) i = j;
    const int local = tile - d.off[i];
    const int gx = d.gx[i];
    float* tb = (float*)lA + grp * 32 * 33;
    trans_tile(d.src[i], d.dst[i], d.K[i], d.N[i],
               (local % gx) * 32, (local / gx) * 32, tt & 31, tt >> 5, tb);
  }
}

// ---------------- 8-phase GEMM body (r10 schedule, proven): BM=BN=256, BK=64, 8 waves ----------------
#define SWZK_(ks) (((ks) * 32 + fq * 8) ^ ((fr & 7) << 3))
#define RD_A(buf, q) { _Pragma("unroll") for (int mf = 0; mf < 4; ++mf) { \
    ar[mf][0] = *(const bf16x8*)&sA[((buf) * 2 + wm) * 8192 + ((q) * 64 + mf * 16 + fr) * 64 + SWZK_(0)]; \
    ar[mf][1] = *(const bf16x8*)&sA[((buf) * 2 + wm) * 8192 + ((q) * 64 + mf * 16 + fr) * 64 + SWZK_(1)]; } }
#define RD_B(buf, nq) { _Pragma("unroll") for (int nf = 0; nf < 2; ++nf) { \
    br[nq][nf][0] = *(const bf16x8*)&sB[((buf) * 2 + wbh) * 8192 + (wbr + (nq) * 32 + nf * 16 + fr) * 64 + SWZK_(0)]; \
    br[nq][nf][1] = *(const bf16x8*)&sB[((buf) * 2 + wbh) * 8192 + (wbr + (nq) * 32 + nf * 16 + fr) * 64 + SWZK_(1)]; } }
#define MFMA_Q(mq, nq) { __builtin_amdgcn_s_setprio(1); \
  _Pragma("unroll") for (int mf = 0; mf < 4; ++mf) \
  _Pragma("unroll") for (int nf = 0; nf < 2; ++nf) { \
    acc[(mq)*4+mf][(nq)*2+nf] = __builtin_amdgcn_mfma_f32_16x16x32_bf16(ar[mf][0], br[nq][nf][0], acc[(mq)*4+mf][(nq)*2+nf], 0, 0, 0); \
    acc[(mq)*4+mf][(nq)*2+nf] = __builtin_amdgcn_mfma_f32_16x16x32_bf16(ar[mf][1], br[nq][nf][1], acc[(mq)*4+mf][(nq)*2+nf], 0, 0, 0); } \
  __builtin_amdgcn_s_setprio(0); }
#define SBAR_ __builtin_amdgcn_sched_barrier(0)
#define HBAR_ __builtin_amdgcn_s_barrier()

template <typename CT>
__device__ __forceinline__ void ph8_body(
    const bf16_t* __restrict__ A, const bf16_t* __restrict__ Bt, CT* __restrict__ C,
    int N, int K, int row0, int col0, int ropeCol0, int posMask, bf16_t* sA, bf16_t* sB) {
  const int tid = threadIdx.x;
  const int w = tid >> 6, lane = tid & 63;
  const int wm = w >> 2, wn = w & 3;          // 2M x 4N waves, wave tile 128x64
  const int lr = lane >> 3;
  const int kswz = ((lane & 7) ^ lr) * 8;     // pre-swizzled global k-offset
  const int nt = K >> 6;
  const int fr = lane & 15, fq = lane >> 4;
  const int wbh = wn >> 1;                    // B LDS half this wave reads
  const int wbr = (wn & 1) * 64;              // row base within that half

  auto stA = [&](int t, int h, int buf) {     // stage A half-tile (128 rows x 64 k)
    const bf16_t* g = A + (size_t)(row0 + h * 128 + w * 8 + lr) * K + (t << 6) + kswz;
    gld_lds16(g, sA + (buf * 2 + h) * 8192 + w * 512);
    gld_lds16(g + (size_t)64 * K, sA + (buf * 2 + h) * 8192 + 4096 + w * 512);
  };
  auto stB = [&](int t, int h, int buf) {
    const bf16_t* g = Bt + (size_t)(col0 + h * 128 + w * 8 + lr) * K + (t << 6) + kswz;
    gld_lds16(g, sB + (buf * 2 + h) * 8192 + w * 512);
    gld_lds16(g + (size_t)64 * K, sB + (buf * 2 + h) * 8192 + 4096 + w * 512);
  };

  bf16x8 ar[4][2], br[2][2][2];   // A quad (reused across 2 phases), both B quads kept
  f32x4 acc[8][4];
#pragma unroll
  for (int i = 0; i < 8; ++i)
#pragma unroll
    for (int j = 0; j < 4; ++j) acc[i][j] = f32x4{0.f, 0.f, 0.f, 0.f};

  // prologue: tile 0 fully + B halves of tile 1
  stA(0, 0, 0); stA(0, 1, 0); stB(0, 0, 0); stB(0, 1, 0);
  stB(1, 0, 1); stB(1, 1, 1);
  asm volatile("s_waitcnt vmcnt(4)" ::: "memory");  // tile 0's 4 halves landed
  SBAR_; HBAR_;

  for (int t = 0; t < nt; ++t) {
    const int buf = t & 1;
    // ---- ph0: read A(m0)+B(n0); stage A0(t+1) ----
    SBAR_;
    RD_A(buf, 0); RD_B(buf, 0);
    if (t + 1 < nt) stA(t + 1, 0, buf ^ 1);
    SBAR_; HBAR_;
    MFMA_Q(0, 0);
    SBAR_; HBAR_;
    // ---- ph1: read B(n1); stage A1(t+1) ----
    SBAR_;
    RD_B(buf, 1);
    if (t + 1 < nt) stA(t + 1, 1, buf ^ 1);
    SBAR_; HBAR_;
    MFMA_Q(0, 1);
    SBAR_; HBAR_;
    // ---- ph2: read A(m1); stage B0(t+2) over consumed B0 ----
    SBAR_;
    RD_A(buf, 1);
    if (t + 2 < nt) stB(t + 2, 0, buf);
    SBAR_; HBAR_;
    MFMA_Q(1, 1);
    SBAR_; HBAR_;
    // ---- ph3: no reads (B(n0) held in regs); stage B1(t+2); counted vmcnt ----
    SBAR_;
    if (t + 2 < nt) {
      stB(t + 2, 1, buf);
      asm volatile("s_waitcnt vmcnt(4)" ::: "memory");  // all of tile t+1 landed
    } else {
      asm volatile("s_waitcnt vmcnt(0)" ::: "memory");  // drain tail
    }
    SBAR_; HBAR_; SBAR_;
    MFMA_Q(1, 0);
    SBAR_; HBAR_;
  }

  // epilogue: 16x16x32 C-layout col=lane&15, row=(lane>>4)*4+r
  if (col0 >= ropeCol0) {
    // RoPE rotation, same-lane pairs; freq j = (nfg&1)*16 + fr; pos = row & posMask
    const float if0 = fexp((float)fr * NL_ROPE);
    const float if1 = fexp((float)(fr + 16) * NL_ROPE);
    const size_t cbase = (size_t)col0 + wn * 64 + fr;
#pragma unroll
    for (int mfg = 0; mfg < 8; ++mfg)
#pragma unroll
      for (int r = 0; r < 4; ++r) {
        const int row = row0 + wm * 128 + mfg * 16 + fq * 4 + r;
        const float pos = (float)(row & posMask);
        float s0, c0, s1, c1;
        fsincos(pos * if0, &s0, &c0);
        fsincos(pos * if1, &s1, &c1);
        const float lo0 = acc[mfg][0][r], hi0 = acc[mfg][2][r];
        const float lo1 = acc[mfg][1][r], hi1 = acc[mfg][3][r];
        CT* cr = C + (size_t)row * N + cbase;
        cr[0]  = (CT)(lo0 * c0 - hi0 * s0);
        cr[16] = (CT)(lo1 * c1 - hi1 * s1);
        cr[32] = (CT)(lo0 * s0 + hi0 * c0);
        cr[48] = (CT)(lo1 * s1 + hi1 * c1);
      }
    return;
  }
#pragma unroll
  for (int mfg = 0; mfg < 8; ++mfg)
#pragma unroll
    for (int nfg = 0; nfg < 4; ++nfg) {
      const int col = col0 + wn * 64 + (nfg >> 1) * 32 + (nfg & 1) * 16 + fr;
#pragma unroll
      for (int r = 0; r < 4; ++r) {
        const int row = row0 + wm * 128 + mfg * 16 + fq * 4 + r;
        C[(size_t)row * N + col] = (CT)acc[mfg][nfg][r];
      }
    }
}

// ---------------- standalone 8-phase kernel (XCD-swizzled 2D grid) ----------------
template <typename CT>
__global__ __launch_bounds__(512, 2) void gemm_8ph(
    const bf16_t* __restrict__ A, const bf16_t* __restrict__ Bt,
    CT* __restrict__ C, int M, int N, int K) {
  __shared__ __align__(16) bf16_t sA[2 * 2 * 128 * 64];
  __shared__ __align__(16) bf16_t sB[2 * 2 * 128 * 64];
  const int gx = gridDim.x;
  const int nwg = gx * gridDim.y;
  const int orig = blockIdx.y * gx + blockIdx.x;
  const int wg = (orig & 7) * (nwg >> 3) + (orig >> 3);
  const int bx = wg % gx, by = wg / gx;
  ph8_body<CT>(A, Bt, C, N, K, by * 256, bx * 256, 1 << 30, 0, sA, sB);
}

// ---------------- fused up-projection: q_uqr + kv_comb, BOTH on the 8ph path ----------------
// LPT dispatch order: q_uqr (12 K-tiles/block, 384 blocks) first; kv_comb (8 kt, 136) last.
// Bijective XCD swizzle within each partition (384=8x48, 136=8x17).
__global__ __launch_bounds__(512, 2) void gemm_up_fused(
    const bf16_t* __restrict__ A0, const bf16_t* __restrict__ B0, bf16_t* __restrict__ C0,
    int N0, int K0, int gx0,
    const bf16_t* __restrict__ A1, const bf16_t* __restrict__ B1, bf16_t* __restrict__ C1,
    int N1, int K1, int gx1, int split) {
  __shared__ __align__(16) bf16_t sA[2 * 2 * 128 * 64];
  __shared__ __align__(16) bf16_t sB[2 * 2 * 128 * 64];
  const int orig = blockIdx.x;
  if (orig < split) {
    const int wg = (orig & 7) * (split >> 3) + (orig >> 3);
    ph8_body<bf16_t>(A0, B0, C0, N0, K0, (wg / gx0) * 256, (wg % gx0) * 256, 2048, LQ - 1, sA, sB);
  } else {
    const int l = orig - split;
    const int n1 = gridDim.x - split;
    const int wg = (l & 7) * (n1 >> 3) + (l >> 3);
    ph8_body<bf16_t>(A1, B1, C1, N1, K1, (wg / gx1) * 256, (wg % gx1) * 256, 4096, LK - 1, sA, sB);
  }
}

// ---------------- sparse windowed attention + packed WoT transpose ----------------
// Blocks [0,NATT): attention (1 wave/query, 4 queries/block).
// Blocks [NATT, NATT+WO_TILES): W_o (2048x2048) -> WoT transpose tiles (needed only
// by the W_o GEMM launched after this kernel). Block-uniform branch.
__global__ __launch_bounds__(256) void attn_sparse(
    const bf16_t* __restrict__ qc, const bf16_t* __restrict__ kvc,
    const int* __restrict__ seg, bf16_t* __restrict__ out,
    const float* __restrict__ Wo, bf16_t* __restrict__ WoT) {
  __shared__ float tl[32 * 33];
  if (blockIdx.x >= NATT) {
    const int tile = blockIdx.x - NATT;
    trans_tile(Wo, WoT, H_ * HD_, QDIM, (tile & 63) * 32, (tile >> 6) * 32,
               threadIdx.x & 31, threadIdx.x >> 5, tl);
    return;
  }
  const int qrow = blockIdx.x * 4 + (threadIdx.x >> 6);  // b*LQ + qi
  const int lane = threadIdx.x & 63;
  const int h = lane >> 2, sub = lane & 3;
  const int b = qrow >> 12;  // / LQ
  const int s = seg[qrow];
  const int kl = max(0, s - 8);
  const float scale = 0.07216878364870322f;  // 1/sqrt(HD+R)

  float qnf[32], qrf[16];
  {
    const bf16_t* p = qc + (size_t)qrow * QCOMB + h * HD_ + sub * 32;
#pragma unroll
    for (int j = 0; j < 4; ++j) {
      bf16x8 t = *(const bf16x8*)(p + j * 8);
#pragma unroll
      for (int e = 0; e < 8; ++e) qnf[j * 8 + e] = (float)t[e];
    }
    const bf16_t* p2 = qc + (size_t)qrow * QCOMB + 2048 + h * R_ + sub * 16;
#pragma unroll
    for (int j = 0; j < 2; ++j) {
      bf16x8 t = *(const bf16x8*)(p2 + j * 8);
#pragma unroll
      for (int e = 0; e < 8; ++e) qrf[j * 8 + e] = (float)t[e];
    }
  }

  float sc[9];
#pragma unroll
  for (int kk = 0; kk < 9; ++kk) {
    const int kx = kl + kk;
    const bf16_t* kb = kvc + (size_t)(b * LK + kx) * KCOMB;
    float d = 0.f;
    const bf16_t* p = kb + h * HD_ + sub * 32;
#pragma unroll
    for (int j = 0; j < 4; ++j) {
      bf16x8 t = *(const bf16x8*)(p + j * 8);
#pragma unroll
      for (int e = 0; e < 8; ++e) d += qnf[j * 8 + e] * (float)t[e];
    }
    const bf16_t* p2 = kb + 4096 + sub * 16;
#pragma unroll
    for (int j = 0; j < 2; ++j) {
      bf16x8 t = *(const bf16x8*)(p2 + j * 8);
#pragma unroll
      for (int e = 0; e < 8; ++e) d += qrf[j * 8 + e] * (float)t[e];
    }
    d += __shfl_xor(d, 1);
    d += __shfl_xor(d, 2);
    sc[kk] = (kx <= s) ? d * scale : -1e30f;
  }
  float m = sc[0];
#pragma unroll
  for (int kk = 1; kk < 9; ++kk) m = fmaxf(m, sc[kk]);
  float sum = 0.f;
#pragma unroll
  for (int kk = 0; kk < 9; ++kk) { const float p = expf(sc[kk] - m); sc[kk] = p; sum += p; }
  const float inv = 1.f / sum;

  float o[32];
#pragma unroll
  for (int j = 0; j < 32; ++j) o[j] = 0.f;
#pragma unroll
  for (int kk = 0; kk < 9; ++kk) {
    const bf16_t* pv = kvc + (size_t)(b * LK + kl + kk) * KCOMB + 2048 + h * HD_ + sub * 32;
    const float p = sc[kk] * inv;
#pragma unroll
    for (int j = 0; j < 4; ++j) {
      bf16x8 t = *(const bf16x8*)(pv + j * 8);
#pragma unroll
      for (int e = 0; e < 8; ++e) o[j * 8 + e] += p * (float)t[e];
    }
  }
  bf16_t* po = out + (size_t)qrow * (H_ * HD_) + h * HD_ + sub * 32;
#pragma unroll
  for (int j = 0; j < 4; ++j) {
    bf16x8 t;
#pragma unroll
    for (int e = 0; e < 8; ++e) t[e] = (bf16_t)o[j * 8 + e];
    *(bf16x8*)(po + j * 8) = t;
  }
}

extern "C" void kernel_launch(void* const* d_in, const int* in_sizes, int n_in,
                              void* d_out, int out_size, void* d_ws, size_t ws_size,
                              hipStream_t stream) {
  const float* q     = (const float*)d_in[0];
  const float* kv    = (const float*)d_in[1];
  const int*   seg   = (const int*)d_in[2];
  const float* W_kvc = (const float*)d_in[3];
  const float* W_dq  = (const float*)d_in[4];
  const float* W_uq  = (const float*)d_in[5];
  const float* W_qr  = (const float*)d_in[6];
  const float* W_uk  = (const float*)d_in[7];
  const float* W_kr  = (const float*)d_in[8];
  const float* W_uv  = (const float*)d_in[9];
  const float* W_o   = (const float*)d_in[10];
  float* out = (float*)d_out;
  (void)in_sizes; (void)n_in; (void)out_size; (void)ws_size;

  char* ws = (char*)d_ws;
  size_t off = 0;
  auto alloc = [&](size_t bytes) {
    char* p = ws + off;
    off = (off + bytes + 255) & ~(size_t)255;
    return p;
  };
  bf16_t* q_bf    = (bf16_t*)alloc((size_t)B_ * LQ * QDIM * 2);   // reused as attn_o
  bf16_t* kv_bf   = (bf16_t*)alloc((size_t)B_ * LK * KVDIM * 2);
  bf16_t* WkvcT   = (bf16_t*)alloc((size_t)KVC_ * KVDIM * 2);
  bf16_t* WdqT    = (bf16_t*)alloc((size_t)QC_ * QDIM * 2);
  bf16_t* WuqrT   = (bf16_t*)alloc((size_t)QCOMB * QC_ * 2);      // [W_uq^T ; W_qr^T]
  bf16_t* WkvT    = (bf16_t*)alloc((size_t)KCOMB * KVC_ * 2);     // [W_uk^T ; W_uv^T ; W_kr^T ; pad]
  bf16_t* WoT     = (bf16_t*)alloc((size_t)QDIM * (H_ * HD_) * 2);
  bf16_t* kv_c    = (bf16_t*)alloc((size_t)B_ * LK * KVC_ * 2);
  bf16_t* q_c     = (bf16_t*)alloc((size_t)B_ * LQ * QC_ * 2);
  bf16_t* q_comb  = (bf16_t*)alloc((size_t)B_ * LQ * QCOMB * 2);
  bf16_t* kv_comb = (bf16_t*)alloc((size_t)B_ * LK * KCOMB * 2);
  bf16_t* attn_o  = q_bf;  // q_bf dead after q_c GEMM

  // ---- prep1: convert inputs + W_kvc/W_dq transposes (what gemm_dual needs) ----
  {
    TransAll d;
    d.src[0] = W_kvc; d.dst[0] = WkvcT; d.K[0] = KVDIM; d.N[0] = KVC_; d.gx[0] = KVC_ / 32;
    d.src[1] = W_dq;  d.dst[1] = WdqT;  d.K[1] = QDIM;  d.N[1] = QC_;  d.gx[1] = QC_ / 32;
    const int t0 = (KVC_ / 32) * (KVDIM / 32);   // 1024
    const int t1 = (QC_ / 32) * (QDIM / 32);     // 1536
    d.off[0] = 0; d.off[1] = t0;
    for (int j = 2; j <= 8; ++j) d.off[j] = t0 + t1;
    for (int j = 2; j < 8; ++j) { d.src[j] = W_kvc; d.dst[j] = WkvcT; d.K[j] = 32; d.N[j] = 32; d.gx[j] = 1; }
    prep_all<<<NCVT + t0 + t1, 256, 0, stream>>>(
        q, q_bf, (long)B_ * LQ * QDIM, kv, kv_bf, (long)B_ * LK * KVDIM, d);
  }

  // ---- dual GEMM (q_dq 192 blk + kv_c 32 blk) + packed up-weight transposes ----
  {
    TransAll d;
    auto set = [&](int i, int prev_off, const float* s, bf16_t* dt, int K, int N) {
      d.src[i] = s; d.dst[i] = dt; d.K[i] = K; d.N[i] = N; d.gx[i] = N / 32;
      d.off[i] = prev_off;
      return prev_off + (N / 32) * (K / 32);
    };
    int o2 = 0;
    o2 = set(0, o2, W_uq, WuqrT, QC_, H_ * HD_);                                  // 1536
    o2 = set(1, o2, W_qr, WuqrT + (size_t)(H_ * HD_) * QC_, QC_, H_ * R_);        //  768
    o2 = set(2, o2, W_uk, WkvT, KVC_, H_ * HD_);                                  // 1024
    o2 = set(3, o2, W_uv, WkvT + (size_t)(H_ * HD_) * KVC_, KVC_, H_ * HD_);      // 1024
    o2 = set(4, o2, W_kr, WkvT + (size_t)2 * (H_ * HD_) * KVC_, KVC_, R_);        //   32
    for (int j = 5; j <= 8; ++j) d.off[j] = o2;                                   // 4384 total (even)
    for (int j = 5; j < 8; ++j) { d.src[j] = W_uq; d.dst[j] = WuqrT; d.K[j] = 32; d.N[j] = 32; d.gx[j] = 1; }
    gemm_dual_prep<<<224 + o2 / 2, 512, 0, stream>>>(
        q_bf, WdqT, q_c, QC_, QDIM,
        kv_bf, WkvcT, kv_c, KVC_, KVDIM, d);
  }

  // ---- fused up-projections, both 8ph, LPT-ordered: q_uqr (384) first, kv_comb (136) last ----
  gemm_up_fused<<<520, 512, 0, stream>>>(
      q_c, WuqrT, q_comb, QCOMB, QC_, QCOMB / 256,
      kv_c, WkvT, kv_comb, KCOMB, KVC_, KCOMB / 256, 384);

  // ---- sparse attention + packed WoT transpose ----
  attn_sparse<<<NATT + WO_TILES, 256, 0, stream>>>(q_comb, kv_comb, seg, attn_o, W_o, WoT);

  // ---- output projection ----
  gemm_8ph<float><<<dim3(QDIM / 256, (B_ * LQ) / 256), 512, 0, stream>>>(
      attn_o, WoT, out, B_ * LQ, QDIM, H_ * HD_);
}

// Round 17
// 274.878 us; speedup vs baseline: 1.0382x; 1.0382x over previous
//
#include <hip/hip_runtime.h>
#include <math.h>

typedef __bf16 bf16_t;
typedef __bf16 bf16x8 __attribute__((ext_vector_type(8)));
typedef float f32x4 __attribute__((ext_vector_type(4)));

#define B_    2
#define LQ    4096
#define LK    1024
#define QDIM  2048
#define KVDIM 2048
#define H_    16
#define HD_   128
#define KVC_  512
#define QC_   768
#define R_    64

// fused row widths
#define QCOMB 3072   // [q_nope(2048) | q_rope(1024)]
#define KCOMB 4352   // [k_nope(2048) | v(2048) | k_rope(64) | pad(192)] -- 17x256 tiles

#define NL_ROPE (-9.210340371976184f / 32.0f)   // -ln(10000)/half

typedef __attribute__((address_space(1))) void gvoid_t;
typedef __attribute__((address_space(3))) void lvoid_t;

static __device__ __forceinline__ void gld_lds16(const void* g, void* l) {
  __builtin_amdgcn_global_load_lds((gvoid_t*)(void*)g, (lvoid_t*)l, 16, 0, 0);
}

// inline hw transcendentals (no libm calls -> no spills around epilogue trig)
static __device__ __forceinline__ float fexp(float x) {
  return __builtin_amdgcn_exp2f(x * 1.4426950408889634f);   // v_exp_f32
}
static __device__ __forceinline__ void fsincos(float ang, float* s, float* c) {
  float rev = ang * 0.15915494309189535f;                   // radians -> revolutions
  rev -= floorf(rev);                                       // reduce to [0,1) (hw range)
  *s = __builtin_amdgcn_sinf(rev);                          // v_sin_f32: sin(2*pi*rev)
  *c = __builtin_amdgcn_cosf(rev);                          // v_cos_f32
}

// ---------------- prep: fp32->bf16 convert (q,kv) + ALL weight transposes, 1 launch ----------------
struct TransAll {
  const float* src[8];
  bf16_t* dst[8];
  int K[8], N[8], gx[8];
  int off[9];
};

#define NCVT 4096
__global__ __launch_bounds__(256) void prep_all(
    const float* __restrict__ qa, bf16_t* __restrict__ oq, long nq,
    const float* __restrict__ kva, bf16_t* __restrict__ okv, long nkv,
    TransAll d) {
  __shared__ float t[32][33];
  const int bid = blockIdx.x;
  if (bid < NCVT) {
    const long stride = (long)NCVT * 256 * 8;
    for (long i = ((long)bid * 256 + threadIdx.x) * 8; i < nq; i += stride) {
      float4 x = *(const float4*)(qa + i);
      float4 y = *(const float4*)(qa + i + 4);
      bf16x8 v;
      v[0] = (bf16_t)x.x; v[1] = (bf16_t)x.y; v[2] = (bf16_t)x.z; v[3] = (bf16_t)x.w;
      v[4] = (bf16_t)y.x; v[5] = (bf16_t)y.y; v[6] = (bf16_t)y.z; v[7] = (bf16_t)y.w;
      *(bf16x8*)(oq + i) = v;
    }
    for (long i = ((long)bid * 256 + threadIdx.x) * 8; i < nkv; i += stride) {
      float4 x = *(const float4*)(kva + i);
      float4 y = *(const float4*)(kva + i + 4);
      bf16x8 v;
      v[0] = (bf16_t)x.x; v[1] = (bf16_t)x.y; v[2] = (bf16_t)x.z; v[3] = (bf16_t)x.w;
      v[4] = (bf16_t)y.x; v[5] = (bf16_t)y.y; v[6] = (bf16_t)y.z; v[7] = (bf16_t)y.w;
      *(bf16x8*)(okv + i) = v;
    }
    return;
  }
  const int tb = bid - NCVT;
  int i = 0;
#pragma unroll
  for (int j = 1; j < 8; ++j) if (tb >= d.off[j]) i = j;
  const float* __restrict__ src = d.src[i];
  bf16_t* __restrict__ dst = d.dst[i];
  const int K = d.K[i], N = d.N[i];
  const int local = tb - d.off[i];
  const int gx = d.gx[i];
  const int bx = (local % gx) * 32, by = (local / gx) * 32;
  const int x = threadIdx.x & 31, y = threadIdx.x >> 5;
#pragma unroll
  for (int j = 0; j < 32; j += 8)
    t[y + j][x] = src[(size_t)(by + y + j) * N + bx + x];
  __syncthreads();
#pragma unroll
  for (int j = 0; j < 32; j += 8)
    dst[(size_t)(bx + y + j) * K + by + x] = (bf16_t)t[x][y + j];
}

// ---------------- big2 pipeline body: BM=256, BN=TN, BK=64, 8 waves (2Mx4N) ----------------
template <int TN, typename CT>
__device__ __forceinline__ void big2_body(
    const bf16_t* __restrict__ A, const bf16_t* __restrict__ Bt, CT* __restrict__ C,
    int N, int K, int row0, int col0, bf16_t* lA, bf16_t* lB) {
  constexpr int NF = TN / 64;
  constexpr int LW = 4 + TN / 64;
  const int tid = threadIdx.x;
  const int w = tid >> 6, lane = tid & 63;
  const int wm = w >> 2, wn = w & 3;
  const int lr = lane >> 3;
  const int kswz = ((lane & 7) ^ lr) * 8;
  const int nt = K >> 6;
  const int fr = lane & 15, fq = lane >> 4;

  auto STAGE = [&](int t, int buf) {
    const int k0 = t << 6;
#pragma unroll
    for (int j = 0; j < 4; ++j) {
      const int s = j * 8 + w;
      gld_lds16(A + (size_t)(row0 + s * 8 + lr) * K + k0 + kswz, &lA[buf * 256 * 64 + s * 512]);
    }
#pragma unroll
    for (int j = 0; j < TN / 64; ++j) {
      const int s = j * 8 + w;
      gld_lds16(Bt + (size_t)(col0 + s * 8 + lr) * K + k0 + kswz, &lB[buf * TN * 64 + s * 512]);
    }
  };

  bf16x8 aA[8], bA[NF], aB[8], bB[NF];
  f32x4 acc[8][NF];
#pragma unroll
  for (int i = 0; i < 8; ++i)
#pragma unroll
    for (int j = 0; j < NF; ++j) acc[i][j] = f32x4{0.f, 0.f, 0.f, 0.f};

  auto READ = [&](int buf, int kk, bf16x8* a, bf16x8* b) {
    const int swzk = (kk * 32 + fq * 8) ^ ((fr & 7) << 3);
#pragma unroll
    for (int mf = 0; mf < 8; ++mf)
      a[mf] = *(const bf16x8*)&lA[buf * 256 * 64 + (wm * 128 + mf * 16 + fr) * 64 + swzk];
#pragma unroll
    for (int nf = 0; nf < NF; ++nf)
      b[nf] = *(const bf16x8*)&lB[buf * TN * 64 + (wn * (TN / 4) + nf * 16 + fr) * 64 + swzk];
  };
  auto MF = [&](bf16x8* a, bf16x8* b) {
    __builtin_amdgcn_s_setprio(1);
#pragma unroll
    for (int mf = 0; mf < 8; ++mf)
#pragma unroll
      for (int nf = 0; nf < NF; ++nf)
        acc[mf][nf] = __builtin_amdgcn_mfma_f32_16x16x32_bf16(a[mf], b[nf], acc[mf][nf], 0, 0, 0);
    __builtin_amdgcn_s_setprio(0);
  };

  STAGE(0, 0);
  STAGE(1, 1);
  if constexpr (LW == 8) { asm volatile("s_waitcnt vmcnt(8)" ::: "memory"); }
  else                   { asm volatile("s_waitcnt vmcnt(6)" ::: "memory"); }
  __builtin_amdgcn_sched_barrier(0);
  __builtin_amdgcn_s_barrier();
  READ(0, 0, aA, bA);

  for (int t = 0; t < nt; ++t) {
    const int buf = t & 1;
    READ(buf, 1, aB, bB);
    __builtin_amdgcn_sched_barrier(0);
    MF(aA, bA);
    asm volatile("s_waitcnt lgkmcnt(0)" ::: "memory");
    __builtin_amdgcn_sched_barrier(0);
    __builtin_amdgcn_s_barrier();
    if (t + 2 < nt) {
      STAGE(t + 2, buf);
      if constexpr (LW == 8) { asm volatile("s_waitcnt vmcnt(8)" ::: "memory"); }
      else                   { asm volatile("s_waitcnt vmcnt(6)" ::: "memory"); }
    } else {
      asm volatile("s_waitcnt vmcnt(0)" ::: "memory");
    }
    __builtin_amdgcn_sched_barrier(0);
    __builtin_amdgcn_s_barrier();
    if (t + 1 < nt) READ(buf ^ 1, 0, aA, bA);
    __builtin_amdgcn_sched_barrier(0);
    MF(aB, bB);
  }

#pragma unroll
  for (int mf = 0; mf < 8; ++mf)
#pragma unroll
    for (int nf = 0; nf < NF; ++nf) {
      const int col = col0 + wn * (TN / 4) + nf * 16 + fr;
#pragma unroll
      for (int r = 0; r < 4; ++r) {
        const int row = row0 + wm * 128 + mf * 16 + fq * 4 + r;
        C[(size_t)row * N + col] = (CT)acc[mf][nf][r];
      }
    }
}

// ---------------- dual big2 kernel: two independent GEMMs in one launch ----------------
__global__ __launch_bounds__(512, 2) void gemm_dual(
    const bf16_t* __restrict__ A0, const bf16_t* __restrict__ B0, bf16_t* __restrict__ C0,
    int N0, int K0,
    const bf16_t* __restrict__ A1, const bf16_t* __restrict__ B1, bf16_t* __restrict__ C1,
    int N1, int K1, int split) {
  __shared__ __align__(16) bf16_t lA[2 * 256 * 64];
  __shared__ __align__(16) bf16_t lB[2 * 128 * 64];
  const int nwg = gridDim.x;
  const int orig = blockIdx.x;
  const int wg = (orig & 7) * (nwg >> 3) + (orig >> 3);
  if (wg < split) {
    const int gx = N0 / 128;
    big2_body<128, bf16_t>(A0, B0, C0, N0, K0, (wg / gx) * 256, (wg % gx) * 128, lA, lB);
  } else {
    const int l = wg - split;
    const int gx = N1 / 128;
    big2_body<128, bf16_t>(A1, B1, C1, N1, K1, (l / gx) * 256, (l % gx) * 128, lA, lB);
  }
}

// ---------------- 8-phase GEMM body (r10 schedule, proven): BM=BN=256, BK=64, 8 waves ----------------
// ropeCol0: col-tiles with col0 >= ropeCol0 get the RoPE epilogue (same-lane pairs:
// acc[mfg][0]<->acc[mfg][2], acc[mfg][1]<->acc[mfg][3]); pos = row & posMask.
#define SWZK_(ks) (((ks) * 32 + fq * 8) ^ ((fr & 7) << 3))
#define RD_A(buf, q) { _Pragma("unroll") for (int mf = 0; mf < 4; ++mf) { \
    ar[mf][0] = *(const bf16x8*)&sA[((buf) * 2 + wm) * 8192 + ((q) * 64 + mf * 16 + fr) * 64 + SWZK_(0)]; \
    ar[mf][1] = *(const bf16x8*)&sA[((buf) * 2 + wm) * 8192 + ((q) * 64 + mf * 16 + fr) * 64 + SWZK_(1)]; } }
#define RD_B(buf, nq) { _Pragma("unroll") for (int nf = 0; nf < 2; ++nf) { \
    br[nq][nf][0] = *(const bf16x8*)&sB[((buf) * 2 + wbh) * 8192 + (wbr + (nq) * 32 + nf * 16 + fr) * 64 + SWZK_(0)]; \
    br[nq][nf][1] = *(const bf16x8*)&sB[((buf) * 2 + wbh) * 8192 + (wbr + (nq) * 32 + nf * 16 + fr) * 64 + SWZK_(1)]; } }
#define MFMA_Q(mq, nq) { __builtin_amdgcn_s_setprio(1); \
  _Pragma("unroll") for (int mf = 0; mf < 4; ++mf) \
  _Pragma("unroll") for (int nf = 0; nf < 2; ++nf) { \
    acc[(mq)*4+mf][(nq)*2+nf] = __builtin_amdgcn_mfma_f32_16x16x32_bf16(ar[mf][0], br[nq][nf][0], acc[(mq)*4+mf][(nq)*2+nf], 0, 0, 0); \
    acc[(mq)*4+mf][(nq)*2+nf] = __builtin_amdgcn_mfma_f32_16x16x32_bf16(ar[mf][1], br[nq][nf][1], acc[(mq)*4+mf][(nq)*2+nf], 0, 0, 0); } \
  __builtin_amdgcn_s_setprio(0); }
#define SBAR_ __builtin_amdgcn_sched_barrier(0)
#define HBAR_ __builtin_amdgcn_s_barrier()

template <typename CT>
__device__ __forceinline__ void ph8_body(
    const bf16_t* __restrict__ A, const bf16_t* __restrict__ Bt, CT* __restrict__ C,
    int N, int K, int row0, int col0, int ropeCol0, int posMask, bf16_t* sA, bf16_t* sB) {
  const int tid = threadIdx.x;
  const int w = tid >> 6, lane = tid & 63;
  const int wm = w >> 2, wn = w & 3;          // 2M x 4N waves, wave tile 128x64
  const int lr = lane >> 3;
  const int kswz = ((lane & 7) ^ lr) * 8;     // pre-swizzled global k-offset
  const int nt = K >> 6;
  const int fr = lane & 15, fq = lane >> 4;
  const int wbh = wn >> 1;                    // B LDS half this wave reads
  const int wbr = (wn & 1) * 64;              // row base within that half

  auto stA = [&](int t, int h, int buf) {     // stage A half-tile (128 rows x 64 k)
    const bf16_t* g = A + (size_t)(row0 + h * 128 + w * 8 + lr) * K + (t << 6) + kswz;
    gld_lds16(g, sA + (buf * 2 + h) * 8192 + w * 512);
    gld_lds16(g + (size_t)64 * K, sA + (buf * 2 + h) * 8192 + 4096 + w * 512);
  };
  auto stB = [&](int t, int h, int buf) {
    const bf16_t* g = Bt + (size_t)(col0 + h * 128 + w * 8 + lr) * K + (t << 6) + kswz;
    gld_lds16(g, sB + (buf * 2 + h) * 8192 + w * 512);
    gld_lds16(g + (size_t)64 * K, sB + (buf * 2 + h) * 8192 + 4096 + w * 512);
  };

  bf16x8 ar[4][2], br[2][2][2];   // A quad (reused across 2 phases), both B quads kept
  f32x4 acc[8][4];
#pragma unroll
  for (int i = 0; i < 8; ++i)
#pragma unroll
    for (int j = 0; j < 4; ++j) acc[i][j] = f32x4{0.f, 0.f, 0.f, 0.f};

  // prologue: tile 0 fully + B halves of tile 1
  stA(0, 0, 0); stA(0, 1, 0); stB(0, 0, 0); stB(0, 1, 0);
  stB(1, 0, 1); stB(1, 1, 1);
  asm volatile("s_waitcnt vmcnt(4)" ::: "memory");  // tile 0's 4 halves landed
  SBAR_; HBAR_;

  for (int t = 0; t < nt; ++t) {
    const int buf = t & 1;
    // ---- ph0: read A(m0)+B(n0); stage A0(t+1) ----
    SBAR_;
    RD_A(buf, 0); RD_B(buf, 0);
    if (t + 1 < nt) stA(t + 1, 0, buf ^ 1);
    SBAR_; HBAR_;
    MFMA_Q(0, 0);
    SBAR_; HBAR_;
    // ---- ph1: read B(n1); stage A1(t+1) ----
    SBAR_;
    RD_B(buf, 1);
    if (t + 1 < nt) stA(t + 1, 1, buf ^ 1);
    SBAR_; HBAR_;
    MFMA_Q(0, 1);
    SBAR_; HBAR_;
    // ---- ph2: read A(m1); stage B0(t+2) over consumed B0 ----
    SBAR_;
    RD_A(buf, 1);
    if (t + 2 < nt) stB(t + 2, 0, buf);
    SBAR_; HBAR_;
    MFMA_Q(1, 1);
    SBAR_; HBAR_;
    // ---- ph3: no reads (B(n0) held in regs); stage B1(t+2); counted vmcnt ----
    SBAR_;
    if (t + 2 < nt) {
      stB(t + 2, 1, buf);
      asm volatile("s_waitcnt vmcnt(4)" ::: "memory");  // all of tile t+1 landed
    } else {
      asm volatile("s_waitcnt vmcnt(0)" ::: "memory");  // drain tail
    }
    SBAR_; HBAR_; SBAR_;
    MFMA_Q(1, 0);
    SBAR_; HBAR_;
  }

  // epilogue: 16x16x32 C-layout col=lane&15, row=(lane>>4)*4+r
  if (col0 >= ropeCol0) {
    // RoPE rotation, same-lane pairs; freq j = (nfg&1)*16 + fr; pos = row & posMask
    const float if0 = fexp((float)fr * NL_ROPE);
    const float if1 = fexp((float)(fr + 16) * NL_ROPE);
    const size_t cbase = (size_t)col0 + wn * 64 + fr;
#pragma unroll
    for (int mfg = 0; mfg < 8; ++mfg)
#pragma unroll
      for (int r = 0; r < 4; ++r) {
        const int row = row0 + wm * 128 + mfg * 16 + fq * 4 + r;
        const float pos = (float)(row & posMask);
        float s0, c0, s1, c1;
        fsincos(pos * if0, &s0, &c0);
        fsincos(pos * if1, &s1, &c1);
        const float lo0 = acc[mfg][0][r], hi0 = acc[mfg][2][r];
        const float lo1 = acc[mfg][1][r], hi1 = acc[mfg][3][r];
        CT* cr = C + (size_t)row * N + cbase;
        cr[0]  = (CT)(lo0 * c0 - hi0 * s0);
        cr[16] = (CT)(lo1 * c1 - hi1 * s1);
        cr[32] = (CT)(lo0 * s0 + hi0 * c0);
        cr[48] = (CT)(lo1 * s1 + hi1 * c1);
      }
    return;
  }
#pragma unroll
  for (int mfg = 0; mfg < 8; ++mfg)
#pragma unroll
    for (int nfg = 0; nfg < 4; ++nfg) {
      const int col = col0 + wn * 64 + (nfg >> 1) * 32 + (nfg & 1) * 16 + fr;
#pragma unroll
      for (int r = 0; r < 4; ++r) {
        const int row = row0 + wm * 128 + mfg * 16 + fq * 4 + r;
        C[(size_t)row * N + col] = (CT)acc[mfg][nfg][r];
      }
    }
}

// ---------------- standalone 8-phase kernel (XCD-swizzled 2D grid) ----------------
template <typename CT>
__global__ __launch_bounds__(512, 2) void gemm_8ph(
    const bf16_t* __restrict__ A, const bf16_t* __restrict__ Bt,
    CT* __restrict__ C, int M, int N, int K) {
  __shared__ __align__(16) bf16_t sA[2 * 2 * 128 * 64];
  __shared__ __align__(16) bf16_t sB[2 * 2 * 128 * 64];
  const int gx = gridDim.x;
  const int nwg = gx * gridDim.y;
  const int orig = blockIdx.y * gx + blockIdx.x;
  const int wg = (orig & 7) * (nwg >> 3) + (orig >> 3);
  const int bx = wg % gx, by = wg / gx;
  ph8_body<CT>(A, Bt, C, N, K, by * 256, bx * 256, 1 << 30, 0, sA, sB);
}

// ---------------- fused up-projection: q_uqr + kv_comb, BOTH on the 8ph path ----------------
// LPT dispatch order: q_uqr (12 K-tiles/block, 384 blocks) = raw blockIdx [0,split)
// dispatched FIRST; kv_comb (8 K-tiles, 136 blocks) = raw blockIdx [split,nwg) LAST,
// so the short blocks fill the scheduling tail (1 block/CU, ~2 rounds of 256 CUs).
// Bijective XCD swizzle applied WITHIN each partition (384=8x48, 136=8x17).
__global__ __launch_bounds__(512, 2) void gemm_up_fused(
    const bf16_t* __restrict__ A0, const bf16_t* __restrict__ B0, bf16_t* __restrict__ C0,
    int N0, int K0, int gx0,
    const bf16_t* __restrict__ A1, const bf16_t* __restrict__ B1, bf16_t* __restrict__ C1,
    int N1, int K1, int gx1, int split) {
  __shared__ __align__(16) bf16_t sA[2 * 2 * 128 * 64];
  __shared__ __align__(16) bf16_t sB[2 * 2 * 128 * 64];
  const int orig = blockIdx.x;
  if (orig < split) {
    const int wg = (orig & 7) * (split >> 3) + (orig >> 3);
    ph8_body<bf16_t>(A0, B0, C0, N0, K0, (wg / gx0) * 256, (wg % gx0) * 256, 2048, LQ - 1, sA, sB);
  } else {
    const int l = orig - split;
    const int n1 = gridDim.x - split;
    const int wg = (l & 7) * (n1 >> 3) + (l >> 3);
    ph8_body<bf16_t>(A1, B1, C1, N1, K1, (wg / gx1) * 256, (wg % gx1) * 256, 4096, LK - 1, sA, sB);
  }
}

// ---------------- sparse windowed attention: <=9 keys per query ----------------
__global__ __launch_bounds__(256) void attn_sparse(
    const bf16_t* __restrict__ qc, const bf16_t* __restrict__ kvc,
    const int* __restrict__ seg, bf16_t* __restrict__ out) {
  const int qrow = blockIdx.x * 4 + (threadIdx.x >> 6);  // b*LQ + qi
  const int lane = threadIdx.x & 63;
  const int h = lane >> 2, sub = lane & 3;
  const int b = qrow >> 12;  // / LQ
  const int s = seg[qrow];
  const int kl = max(0, s - 8);
  const float scale = 0.07216878364870322f;  // 1/sqrt(HD+R)

  float qnf[32], qrf[16];
  {
    const bf16_t* p = qc + (size_t)qrow * QCOMB + h * HD_ + sub * 32;
#pragma unroll
    for (int j = 0; j < 4; ++j) {
      bf16x8 t = *(const bf16x8*)(p + j * 8);
#pragma unroll
      for (int e = 0; e < 8; ++e) qnf[j * 8 + e] = (float)t[e];
    }
    const bf16_t* p2 = qc + (size_t)qrow * QCOMB + 2048 + h * R_ + sub * 16;
#pragma unroll
    for (int j = 0; j < 2; ++j) {
      bf16x8 t = *(const bf16x8*)(p2 + j * 8);
#pragma unroll
      for (int e = 0; e < 8; ++e) qrf[j * 8 + e] = (float)t[e];
    }
  }

  float sc[9];
#pragma unroll
  for (int kk = 0; kk < 9; ++kk) {
    const int kx = kl + kk;
    const bf16_t* kb = kvc + (size_t)(b * LK + kx) * KCOMB;
    float d = 0.f;
    const bf16_t* p = kb + h * HD_ + sub * 32;
#pragma unroll
    for (int j = 0; j < 4; ++j) {
      bf16x8 t = *(const bf16x8*)(p + j * 8);
#pragma unroll
      for (int e = 0; e < 8; ++e) d += qnf[j * 8 + e] * (float)t[e];
    }
    const bf16_t* p2 = kb + 4096 + sub * 16;
#pragma unroll
    for (int j = 0; j < 2; ++j) {
      bf16x8 t = *(const bf16x8*)(p2 + j * 8);
#pragma unroll
      for (int e = 0; e < 8; ++e) d += qrf[j * 8 + e] * (float)t[e];
    }
    d += __shfl_xor(d, 1);
    d += __shfl_xor(d, 2);
    sc[kk] = (kx <= s) ? d * scale : -1e30f;
  }
  float m = sc[0];
#pragma unroll
  for (int kk = 1; kk < 9; ++kk) m = fmaxf(m, sc[kk]);
  float sum = 0.f;
#pragma unroll
  for (int kk = 0; kk < 9; ++kk) { const float p = expf(sc[kk] - m); sc[kk] = p; sum += p; }
  const float inv = 1.f / sum;

  float o[32];
#pragma unroll
  for (int j = 0; j < 32; ++j) o[j] = 0.f;
#pragma unroll
  for (int kk = 0; kk < 9; ++kk) {
    const bf16_t* pv = kvc + (size_t)(b * LK + kl + kk) * KCOMB + 2048 + h * HD_ + sub * 32;
    const float p = sc[kk] * inv;
#pragma unroll
    for (int j = 0; j < 4; ++j) {
      bf16x8 t = *(const bf16x8*)(pv + j * 8);
#pragma unroll
      for (int e = 0; e < 8; ++e) o[j * 8 + e] += p * (float)t[e];
    }
  }
  bf16_t* po = out + (size_t)qrow * (H_ * HD_) + h * HD_ + sub * 32;
#pragma unroll
  for (int j = 0; j < 4; ++j) {
    bf16x8 t;
#pragma unroll
    for (int e = 0; e < 8; ++e) t[e] = (bf16_t)o[j * 8 + e];
    *(bf16x8*)(po + j * 8) = t;
  }
}

extern "C" void kernel_launch(void* const* d_in, const int* in_sizes, int n_in,
                              void* d_out, int out_size, void* d_ws, size_t ws_size,
                              hipStream_t stream) {
  const float* q     = (const float*)d_in[0];
  const float* kv    = (const float*)d_in[1];
  const int*   seg   = (const int*)d_in[2];
  const float* W_kvc = (const float*)d_in[3];
  const float* W_dq  = (const float*)d_in[4];
  const float* W_uq  = (const float*)d_in[5];
  const float* W_qr  = (const float*)d_in[6];
  const float* W_uk  = (const float*)d_in[7];
  const float* W_kr  = (const float*)d_in[8];
  const float* W_uv  = (const float*)d_in[9];
  const float* W_o   = (const float*)d_in[10];
  float* out = (float*)d_out;
  (void)in_sizes; (void)n_in; (void)out_size; (void)ws_size;

  char* ws = (char*)d_ws;
  size_t off = 0;
  auto alloc = [&](size_t bytes) {
    char* p = ws + off;
    off = (off + bytes + 255) & ~(size_t)255;
    return p;
  };
  bf16_t* q_bf    = (bf16_t*)alloc((size_t)B_ * LQ * QDIM * 2);   // reused as attn_o
  bf16_t* kv_bf   = (bf16_t*)alloc((size_t)B_ * LK * KVDIM * 2);
  bf16_t* WkvcT   = (bf16_t*)alloc((size_t)KVC_ * KVDIM * 2);
  bf16_t* WdqT    = (bf16_t*)alloc((size_t)QC_ * QDIM * 2);
  bf16_t* WuqrT   = (bf16_t*)alloc((size_t)QCOMB * QC_ * 2);      // [W_uq^T ; W_qr^T]
  bf16_t* WkvT    = (bf16_t*)alloc((size_t)KCOMB * KVC_ * 2);     // [W_uk^T ; W_uv^T ; W_kr^T ; pad]
  bf16_t* WoT     = (bf16_t*)alloc((size_t)QDIM * (H_ * HD_) * 2);
  bf16_t* kv_c    = (bf16_t*)alloc((size_t)B_ * LK * KVC_ * 2);
  bf16_t* q_c     = (bf16_t*)alloc((size_t)B_ * LQ * QC_ * 2);
  bf16_t* q_comb  = (bf16_t*)alloc((size_t)B_ * LQ * QCOMB * 2);
  bf16_t* kv_comb = (bf16_t*)alloc((size_t)B_ * LK * KCOMB * 2);
  bf16_t* attn_o  = q_bf;  // q_bf dead after q_c GEMM

  // ---- convert inputs + transpose all weights (1 launch) ----
  {
    TransAll d;
    auto set = [&](int i, const float* s, bf16_t* dt, int K, int N) {
      d.src[i] = s; d.dst[i] = dt; d.K[i] = K; d.N[i] = N; d.gx[i] = N / 32;
    };
    set(0, W_kvc, WkvcT, KVDIM, KVC_);
    set(1, W_dq,  WdqT,  QDIM,  QC_);
    set(2, W_uq,  WuqrT, QC_,   H_ * HD_);
    set(3, W_qr,  WuqrT + (size_t)(H_ * HD_) * QC_, QC_, H_ * R_);
    set(4, W_uk,  WkvT,  KVC_,  H_ * HD_);
    set(5, W_uv,  WkvT + (size_t)(H_ * HD_) * KVC_, KVC_, H_ * HD_);
    set(6, W_kr,  WkvT + (size_t)2 * (H_ * HD_) * KVC_, KVC_, R_);
    set(7, W_o,   WoT,   H_ * HD_, QDIM);
    int acc_off = 0;
    for (int i = 0; i < 8; ++i) {
      d.off[i] = acc_off;
      acc_off += (d.N[i] / 32) * (d.K[i] / 32);
    }
    d.off[8] = acc_off;
    prep_all<<<NCVT + acc_off, 256, 0, stream>>>(
        q, q_bf, (long)B_ * LQ * QDIM, kv, kv_bf, (long)B_ * LK * KVDIM, d);
  }

  // ---- fused kv_c + q_dq GEMM (independent; one launch fills the machine) ----
  gemm_dual<<<224, 512, 0, stream>>>(
      kv_bf, WkvcT, kv_c, KVC_, KVDIM,
      q_bf, WdqT, q_c, QC_, QDIM, 32);

  // ---- fused up-projections, both 8ph, LPT-ordered: q_uqr (384) first, kv_comb (136) last ----
  gemm_up_fused<<<520, 512, 0, stream>>>(
      q_c, WuqrT, q_comb, QCOMB, QC_, QCOMB / 256,
      kv_c, WkvT, kv_comb, KCOMB, KVC_, KCOMB / 256, 384);

  // ---- sparse attention (<=9 keys/query) ----
  attn_sparse<<<(B_ * LQ) / 4, 256, 0, stream>>>(q_comb, kv_comb, seg, attn_o);

  // ---- output projection ----
  gemm_8ph<float><<<dim3(QDIM / 256, (B_ * LQ) / 256), 512, 0, stream>>>(
      attn_o, WoT, out, B_ * LQ, QDIM, H_ * HD_);
}